// Round 2
// baseline (590.586 us; speedup 1.0000x reference)
//
#include <hip/hip_runtime.h>

// ---------------------------------------------------------------------------
// MultiHeadAttention (head-axis attention variant), MI355X gfx950.
// B=4 S=4096 DM=1024 H=16 DEPTH=64.  All heavy math in bf16 MFMA, fp32 accum.
//
// Pipeline (stream-serial; one shared cast buffer Cb):
//   castk(Q)->Cb ; gemm_bt<0>(Cb,WtQ)->qb
//   castk(K)->Cb ; gemm_bt<0>(Cb,WtK)->kb
//   castk(V)->Cb ; gemm_bt<0>(Cb,WtV)->vb
//   attn_k(qb,kb,vb)->Cb
//   gemm_bt<1>(Cb,WtO)-> fp32 out, written twice (tuple return)
//
// ws requirement: 4*33.55MB + 8.39MB = 142,606,336 bytes (guarded below).
// ---------------------------------------------------------------------------

typedef __attribute__((ext_vector_type(8))) short bf16x8;   // 8 bf16 = 4 VGPR
typedef __attribute__((ext_vector_type(4))) float f32x4;

#define MTOK 16384          // B*S tokens
#define KDIM 1024
#define OUT_HALF 16777216   // MTOK*1024 (one output copy)

static __device__ __forceinline__ unsigned short f2bf(float f) {
  // RNE fp32->bf16 (inputs are finite normals; NaN path not needed)
  unsigned u = __float_as_uint(f);
  u += 0x7FFFu + ((u >> 16) & 1u);
  return (unsigned short)(u >> 16);
}

static __device__ __forceinline__ void gload_lds16(const void* g, void* l) {
  // async global->LDS, 16B per lane; LDS dest is wave-uniform base + lane*16
  __builtin_amdgcn_global_load_lds(
      (const __attribute__((address_space(1))) unsigned*)g,
      (__attribute__((address_space(3))) unsigned*)l, 16, 0, 0);
}

// ---------------------------------------------------------------------------
// fp32 -> bf16 elementwise cast, 8 elems/thread (float4 x2 -> bf16x8)
// ---------------------------------------------------------------------------
__global__ __launch_bounds__(256) void castk(const float* __restrict__ in,
                                             unsigned short* __restrict__ out,
                                             int n8) {
  int i = blockIdx.x * 256 + threadIdx.x;
  if (i >= n8) return;
  const float4* p = (const float4*)in + (size_t)i * 2;
  float4 x = p[0], y = p[1];
  bf16x8 o;
  o[0] = f2bf(x.x); o[1] = f2bf(x.y); o[2] = f2bf(x.z); o[3] = f2bf(x.w);
  o[4] = f2bf(y.x); o[5] = f2bf(y.y); o[6] = f2bf(y.z); o[7] = f2bf(y.w);
  *(bf16x8*)(out + (size_t)i * 8) = o;
}

// ---------------------------------------------------------------------------
// Transpose-cast: Wt[n][k] = bf16(W[k][n]) for the 4 weight matrices.
// 64x64 tiles via LDS (+1 pad -> (tx+n)%32 bank pattern, conflict-free).
// grid = (256 tiles, 4 weights)
// ---------------------------------------------------------------------------
__global__ __launch_bounds__(256) void wtrans(const float* __restrict__ W0,
                                              const float* __restrict__ W1,
                                              const float* __restrict__ W2,
                                              const float* __restrict__ W3,
                                              unsigned short* __restrict__ Wt) {
  __shared__ float tile[64][65];
  int w = blockIdx.y;
  const float* W = (w == 0) ? W0 : (w == 1) ? W1 : (w == 2) ? W2 : W3;
  unsigned short* dst = Wt + (size_t)w * (1024 * 1024);
  int tkb = (blockIdx.x >> 4) * 64;  // k-tile base (rows of W)
  int tnb = (blockIdx.x & 15) * 64;  // n-tile base (cols of W)
  int tx = threadIdx.x & 63, ty = threadIdx.x >> 6;
#pragma unroll
  for (int p = 0; p < 16; ++p) {
    int k = ty + p * 4;
    tile[k][tx] = W[(size_t)(tkb + k) * 1024 + tnb + tx];
  }
  __syncthreads();
#pragma unroll
  for (int p = 0; p < 16; ++p) {
    int n = ty + p * 4;
    dst[(size_t)(tnb + n) * 1024 + tkb + tx] = f2bf(tile[tx][n]);
  }
}

// ---------------------------------------------------------------------------
// bf16 GEMM, C[m][n] = sum_k A[m][k]*Bt[n][k] + bias[n]
//   A  : [16384][1024] bf16 row-major
//   Bt : [1024][1024]  bf16 (transposed weight, N-major)
// m97 structure: 128x128 tile, BK=32, 4 waves (2x2 of 64x64), 16x16x32 MFMA,
// global_load_lds(16B) staging double-buffered, single barrier per K-step.
// LDS XOR-swizzle (blk^=row&3, 16B granules) applied via pre-swizzled global
// source (m173): gload_lds writes linearly, ds_read applies the same XOR.
// Swizzled ds_read_b128: 8 lanes per 4-bank quad = conflict-free minimum.
// MODE 0: bf16 store (+bias). MODE 1: fp32 dual store (+bias).
// ---------------------------------------------------------------------------
template <int MODE>
__global__ __launch_bounds__(256) void gemm_bt(
    const unsigned short* __restrict__ A, const unsigned short* __restrict__ Bt,
    const float* __restrict__ bias, unsigned short* __restrict__ Cbf,
    float* __restrict__ Cf) {
  __shared__ unsigned short ldsA[2][128 * 32];
  __shared__ unsigned short ldsB[2][128 * 32];
  const int tid = threadIdx.x;
  const int lane = tid & 63;
  const int wid = tid >> 6;
  const int l15 = lane & 15, gp = lane >> 4;
  const int wr = (wid >> 1) * 64, wc = (wid & 1) * 64;
  const long brow = (long)blockIdx.y * 128;
  const long bcol = (long)blockIdx.x * 128;

  // staging slot j = q*256+tid -> LDS linear slot j (16B each; r=j>>2, blk=j&3)
  // global source block pre-swizzled: bs = (j&3) ^ (r&3)
  const int j0 = tid, j1 = 256 + tid;
  const int r0 = j0 >> 2, b0 = (j0 & 3) ^ (r0 & 3);
  const int r1 = j1 >> 2, b1 = (j1 & 3) ^ (r1 & 3);
  const unsigned short* gA0 = A + (brow + r0) * KDIM + b0 * 8;
  const unsigned short* gA1 = A + (brow + r1) * KDIM + b1 * 8;
  const unsigned short* gB0 = Bt + (bcol + r0) * KDIM + b0 * 8;
  const unsigned short* gB1 = Bt + (bcol + r1) * KDIM + b1 * 8;
  const unsigned ldsOff0 = (unsigned)(wid * 64) * 8;        // shorts
  const unsigned ldsOff1 = (unsigned)(256 + wid * 64) * 8;  // shorts

  f32x4 acc[4][4];
#pragma unroll
  for (int m = 0; m < 4; ++m)
#pragma unroll
    for (int n = 0; n < 4; ++n) acc[m][n] = (f32x4){0.f, 0.f, 0.f, 0.f};

  auto stage = [&](int buf, int kt) {
    const int ko = kt * 32;
    gload_lds16(gA0 + ko, &ldsA[buf][ldsOff0]);
    gload_lds16(gA1 + ko, &ldsA[buf][ldsOff1]);
    gload_lds16(gB0 + ko, &ldsB[buf][ldsOff0]);
    gload_lds16(gB1 + ko, &ldsB[buf][ldsOff1]);
  };

  // fragment read offsets (shorts), swizzled: blk' = gp ^ (row&3)
  unsigned aoff[4], boff[4];
#pragma unroll
  for (int m = 0; m < 4; ++m) {
    int row = wr + m * 16 + l15;
    aoff[m] = (unsigned)(row * 32 + ((gp ^ (row & 3)) * 8));
    int col = wc + m * 16 + l15;
    boff[m] = (unsigned)(col * 32 + ((gp ^ (col & 3)) * 8));
  }

  stage(0, 0);
  for (int kt = 0; kt < 32; ++kt) {
    __syncthreads();  // compiler drains vmcnt (tile landed) + lgkm (reads done)
    if (kt + 1 < 32) stage((kt + 1) & 1, kt + 1);
    const int cur = kt & 1;
    bf16x8 a[4], b[4];
#pragma unroll
    for (int m = 0; m < 4; ++m) a[m] = *(const bf16x8*)&ldsA[cur][aoff[m]];
#pragma unroll
    for (int n = 0; n < 4; ++n) b[n] = *(const bf16x8*)&ldsB[cur][boff[n]];
#pragma unroll
    for (int m = 0; m < 4; ++m)
#pragma unroll
      for (int n = 0; n < 4; ++n)
        acc[m][n] = __builtin_amdgcn_mfma_f32_16x16x32_bf16(a[m], b[n],
                                                            acc[m][n], 0, 0, 0);
  }

  // epilogue: D layout col=lane&15, row=(lane>>4)*4+reg (guide m89)
#pragma unroll
  for (int n = 0; n < 4; ++n) {
    const long col = bcol + wc + n * 16 + l15;
    const float bv = bias[col];
#pragma unroll
    for (int m = 0; m < 4; ++m) {
#pragma unroll
      for (int r = 0; r < 4; ++r) {
        const long row = brow + wr + m * 16 + gp * 4 + r;
        const float v = acc[m][n][r] + bv;
        if constexpr (MODE == 0) {
          Cbf[row * KDIM + col] = f2bf(v);
        } else {
          Cf[row * KDIM + col] = v;
          Cf[row * KDIM + col + OUT_HALF] = v;
        }
      }
    }
  }
}

// ---------------------------------------------------------------------------
// Per-token head-axis attention. One wave per token (4 waves/block).
// S^T = K.Q^T via 2 MFMAs (swapped operands so softmax-over-heads reduces
// with 2 shfl_xor); P redistributed to A-fragment layout by 8 shuffles;
// PV = 4 MFMAs with K padded 16->32 (zeros).
// ---------------------------------------------------------------------------
__global__ __launch_bounds__(256) void attn_k(
    const unsigned short* __restrict__ qb, const unsigned short* __restrict__ kb,
    const unsigned short* __restrict__ vb, const float* __restrict__ mask,
    unsigned short* __restrict__ attn) {
  const int tid = threadIdx.x, lane = tid & 63, w = tid >> 6;
  const long t = (long)blockIdx.x * 4 + w;
  const unsigned short* qr = qb + t * KDIM;
  const unsigned short* kr = kb + t * KDIM;
  const unsigned short* vr = vb + t * KDIM;
  const int l15 = lane & 15, gp = lane >> 4;

  // A-frag = k[g=l15][d], B-frag = q[h=l15][d]; both rows contiguous in memory
  bf16x8 kf0 = *(const bf16x8*)(kr + l15 * 64 + gp * 8);
  bf16x8 kf1 = *(const bf16x8*)(kr + l15 * 64 + 32 + gp * 8);
  bf16x8 qf0 = *(const bf16x8*)(qr + l15 * 64 + gp * 8);
  bf16x8 qf1 = *(const bf16x8*)(qr + l15 * 64 + 32 + gp * 8);
  f32x4 st = {0.f, 0.f, 0.f, 0.f};
  st = __builtin_amdgcn_mfma_f32_16x16x32_bf16(kf0, qf0, st, 0, 0, 0);
  st = __builtin_amdgcn_mfma_f32_16x16x32_bf16(kf1, qf1, st, 0, 0, 0);
  // lane holds S^T[g][h]: h=l15, g=gp*4+r

  float s[4];
  const float* mrow = mask + t * 256 + l15 * 16 + gp * 4;  // mask[t][h][g]
#pragma unroll
  for (int r = 0; r < 4; ++r) s[r] = st[r] * 0.125f - 1e9f * mrow[r];

  // softmax over g (fixed h=l15): local over 4 regs, then lanes ^16, ^32
  float mx = fmaxf(fmaxf(s[0], s[1]), fmaxf(s[2], s[3]));
  mx = fmaxf(mx, __shfl_xor(mx, 16, 64));
  mx = fmaxf(mx, __shfl_xor(mx, 32, 64));
  float p[4], sum = 0.f;
#pragma unroll
  for (int r = 0; r < 4; ++r) { p[r] = __expf(s[r] - mx); sum += p[r]; }
  sum += __shfl_xor(sum, 16, 64);
  sum += __shfl_xor(sum, 32, 64);
  const float inv = 1.0f / sum;
#pragma unroll
  for (int r = 0; r < 4; ++r) p[r] *= inv;

  // A-frag for PV: lane needs P[h=l15][g=gp*8+i]; source lane l15+16*(g>>2),
  // reg g&3.  gp>=2 is the zero K-pad.  (all lanes run the shfl: no divergence)
  bf16x8 pa;
#pragma unroll
  for (int i = 0; i < 8; ++i) {
    const int g = gp * 8 + i;
    const int src = l15 + 16 * ((g >> 2) & 3);
    const float v = __shfl(p[i & 3], src, 64);
    pa[i] = (gp < 2) ? (short)f2bf(v) : (short)0;
  }

#pragma unroll
  for (int nb = 0; nb < 4; ++nb) {
    bf16x8 vf;
#pragma unroll
    for (int i = 0; i < 8; ++i) {
      const int g = gp * 8 + i;
      vf[i] = (gp < 2) ? (short)vr[g * 64 + nb * 16 + l15] : (short)0;
    }
    f32x4 o = {0.f, 0.f, 0.f, 0.f};
    o = __builtin_amdgcn_mfma_f32_16x16x32_bf16(pa, vf, o, 0, 0, 0);
#pragma unroll
    for (int r = 0; r < 4; ++r) {
      const int h = gp * 4 + r;
      attn[t * KDIM + h * 64 + nb * 16 + l15] = f2bf(o[r]);
    }
  }
}

// ---------------------------------------------------------------------------
extern "C" void kernel_launch(void* const* d_in, const int* in_sizes, int n_in,
                              void* d_out, int out_size, void* d_ws,
                              size_t ws_size, hipStream_t stream) {
  const float* Q  = (const float*)d_in[0];
  const float* K  = (const float*)d_in[1];
  const float* V  = (const float*)d_in[2];
  const float* mask = (const float*)d_in[3];
  const float* Wq = (const float*)d_in[4];
  const float* bq = (const float*)d_in[5];
  const float* Wk = (const float*)d_in[6];
  const float* bk = (const float*)d_in[7];
  const float* Wv = (const float*)d_in[8];
  const float* bv = (const float*)d_in[9];
  const float* Wo = (const float*)d_in[10];
  const float* bo = (const float*)d_in[11];
  float* out = (float*)d_out;

  const size_t EL = (size_t)MTOK * KDIM;   // 16.78M elems
  unsigned short* Cb = (unsigned short*)d_ws;  // shared cast / attn buffer
  unsigned short* qb = Cb + EL;
  unsigned short* kb = qb + EL;
  unsigned short* vb = kb + EL;
  unsigned short* Wt = vb + EL;            // 4 x 1M elems

  const size_t need = (4 * EL + 4ul * 1024 * 1024) * 2;  // 142,606,336 B
  if (ws_size < need) return;  // deliberate visible failure if ws too small

  dim3 b256(256);
  dim3 gg(8, 128);  // (N/128, M/128)

  wtrans<<<dim3(256, 4), b256, 0, stream>>>(Wq, Wk, Wv, Wo, Wt);

  castk<<<8192, b256, 0, stream>>>(Q, Cb, 2097152);
  gemm_bt<0><<<gg, b256, 0, stream>>>(Cb, Wt + 0 * 1048576, bq, qb, nullptr);
  castk<<<8192, b256, 0, stream>>>(K, Cb, 2097152);
  gemm_bt<0><<<gg, b256, 0, stream>>>(Cb, Wt + 1 * 1048576, bk, kb, nullptr);
  castk<<<8192, b256, 0, stream>>>(V, Cb, 2097152);
  gemm_bt<0><<<gg, b256, 0, stream>>>(Cb, Wt + 2 * 1048576, bv, vb, nullptr);

  attn_k<<<4096, b256, 0, stream>>>(qb, kb, vb, mask, Cb);

  gemm_bt<1><<<gg, b256, 0, stream>>>(Cb, Wt + 3 * 1048576, bo, nullptr, out);
}

// Round 5
// 559.797 us; speedup vs baseline: 1.0550x; 1.0550x over previous
//
#include <hip/hip_runtime.h>

// ---------------------------------------------------------------------------
// MultiHeadAttention (head-axis attention variant), MI355X gfx950.
// B=4 S=4096 DM=1024 H=16 DEPTH=64.  All heavy math in bf16 MFMA, fp32 accum.
//
// R5 == R4 == R3 (re-audited, unchanged): R3/R4 never benched (broker
// timeouts).  Deltas vs verified R2 (590us):
//   * T1 XCD bijective swizzle on all GEMM grids (L2 A-reuse per XCD)
//   * 3 proj GEMMs fused into one grid.z=3 dispatch; 3 casts into one
//   * attn_k: V path via vectorized loads + wave-private swizzled LDS gather;
//             output via LDS re-layout -> 2 coalesced 16B stores/lane
//
// ws layout: Qb,Kb,Vb,qb,kb,vb (6 x 33.55MB) + Wt (8.39MB) = 209.7MB
// (observed ws_size ~512MB from harness poison fills).  attn out aliases Qb.
// ---------------------------------------------------------------------------

typedef __attribute__((ext_vector_type(8))) short bf16x8;   // 8 bf16 = 4 VGPR
typedef __attribute__((ext_vector_type(4))) float f32x4;

#define MTOK 16384          // B*S tokens
#define KDIM 1024
#define OUT_HALF 16777216   // MTOK*1024 (one output copy)

static __device__ __forceinline__ unsigned short f2bf(float f) {
  unsigned u = __float_as_uint(f);
  u += 0x7FFFu + ((u >> 16) & 1u);
  return (unsigned short)(u >> 16);
}

static __device__ __forceinline__ void gload_lds16(const void* g, void* l) {
  __builtin_amdgcn_global_load_lds(
      (const __attribute__((address_space(1))) unsigned*)g,
      (__attribute__((address_space(3))) unsigned*)l, 16, 0, 0);
}

// ---------------------------------------------------------------------------
// fp32 -> bf16 cast for Q,K,V in one dispatch.  grid (8192, 3)
// ---------------------------------------------------------------------------
__global__ __launch_bounds__(256) void castk3(
    const float* __restrict__ Q, const float* __restrict__ K,
    const float* __restrict__ V, unsigned short* __restrict__ Qb,
    unsigned short* __restrict__ Kb, unsigned short* __restrict__ Vb) {
  const int z = blockIdx.y;
  const float* in = (z == 0) ? Q : (z == 1) ? K : V;
  unsigned short* out = (z == 0) ? Qb : (z == 1) ? Kb : Vb;
  int i = blockIdx.x * 256 + threadIdx.x;   // < 2097152
  const float4* p = (const float4*)in + (size_t)i * 2;
  float4 x = p[0], y = p[1];
  bf16x8 o;
  o[0] = f2bf(x.x); o[1] = f2bf(x.y); o[2] = f2bf(x.z); o[3] = f2bf(x.w);
  o[4] = f2bf(y.x); o[5] = f2bf(y.y); o[6] = f2bf(y.z); o[7] = f2bf(y.w);
  *(bf16x8*)(out + (size_t)i * 8) = o;
}

// ---------------------------------------------------------------------------
// Transpose-cast: Wt[n][k] = bf16(W[k][n]) for the 4 weight matrices.
// ---------------------------------------------------------------------------
__global__ __launch_bounds__(256) void wtrans(const float* __restrict__ W0,
                                              const float* __restrict__ W1,
                                              const float* __restrict__ W2,
                                              const float* __restrict__ W3,
                                              unsigned short* __restrict__ Wt) {
  __shared__ float tile[64][65];
  int w = blockIdx.y;
  const float* W = (w == 0) ? W0 : (w == 1) ? W1 : (w == 2) ? W2 : W3;
  unsigned short* dst = Wt + (size_t)w * (1024 * 1024);
  int tkb = (blockIdx.x >> 4) * 64;
  int tnb = (blockIdx.x & 15) * 64;
  int tx = threadIdx.x & 63, ty = threadIdx.x >> 6;
#pragma unroll
  for (int p = 0; p < 16; ++p) {
    int k = ty + p * 4;
    tile[k][tx] = W[(size_t)(tkb + k) * 1024 + tnb + tx];
  }
  __syncthreads();
#pragma unroll
  for (int p = 0; p < 16; ++p) {
    int n = ty + p * 4;
    dst[(size_t)(tnb + n) * 1024 + tkb + tx] = f2bf(tile[tx][n]);
  }
}

// ---------------------------------------------------------------------------
// bf16 GEMM, C[m][n] = sum_k A[m][k]*Bt[n][k] + bias[n]
// m97 structure (verified R2 @~60-75us/GEMM): 128x128 tile, BK=32, 4 waves,
// 16x16x32 MFMA, global_load_lds(16B) double-buffered, 1 barrier/K-step,
// read-side XOR swizzle via pre-swizzled global source (m173).
// T1: bijective XCD swizzle on linear hw workgroup id (nwg % 8 == 0, m204).
// MODE 0: grid.z=3 selects (A,Bt,bias,out) -> bf16 store.
// MODE 1: fp32 dual store (tuple output).
// ---------------------------------------------------------------------------
template <int MODE, int NWG>
__global__ __launch_bounds__(256) void gemm_bt(
    const unsigned short* __restrict__ A0, const unsigned short* __restrict__ A1,
    const unsigned short* __restrict__ A2, const unsigned short* __restrict__ Btb,
    const float* __restrict__ bias0, const float* __restrict__ bias1,
    const float* __restrict__ bias2, unsigned short* __restrict__ O0,
    unsigned short* __restrict__ O1, unsigned short* __restrict__ O2,
    float* __restrict__ Cf) {
  __shared__ unsigned short ldsA[2][128 * 32];
  __shared__ unsigned short ldsB[2][128 * 32];

  // T1: bijective XCD swizzle.  hw linear id -> contiguous per-XCD chunk
  const int wid = blockIdx.x + (blockIdx.y << 3) + (blockIdx.z << 10);
  const int rid = (wid & 7) * (NWG >> 3) + (wid >> 3);
  const int bx = rid & 7, by = (rid >> 3) & 127, z = rid >> 10;

  const unsigned short* A = (z == 0) ? A0 : (z == 1) ? A1 : A2;
  const unsigned short* Bt = Btb + (size_t)z * 1048576;
  const float* bias = (z == 0) ? bias0 : (z == 1) ? bias1 : bias2;
  unsigned short* Cbf = (z == 0) ? O0 : (z == 1) ? O1 : O2;

  const int tid = threadIdx.x;
  const int lane = tid & 63;
  const int wid4 = tid >> 6;
  const int l15 = lane & 15, gp = lane >> 4;
  const int wr = (wid4 >> 1) * 64, wc = (wid4 & 1) * 64;
  const long brow = (long)by * 128;
  const long bcol = (long)bx * 128;

  // staging slot j -> LDS linear (r=j>>2, blk=j&3); global src pre-swizzled
  const int j0 = tid, j1 = 256 + tid;
  const int r0 = j0 >> 2, b0 = (j0 & 3) ^ (r0 & 3);
  const int r1 = j1 >> 2, b1 = (j1 & 3) ^ (r1 & 3);
  const unsigned short* gA0 = A + (brow + r0) * KDIM + b0 * 8;
  const unsigned short* gA1 = A + (brow + r1) * KDIM + b1 * 8;
  const unsigned short* gB0 = Bt + (bcol + r0) * KDIM + b0 * 8;
  const unsigned short* gB1 = Bt + (bcol + r1) * KDIM + b1 * 8;
  const unsigned ldsOff0 = (unsigned)(wid4 * 64) * 8;
  const unsigned ldsOff1 = (unsigned)(256 + wid4 * 64) * 8;

  f32x4 acc[4][4];
#pragma unroll
  for (int m = 0; m < 4; ++m)
#pragma unroll
    for (int n = 0; n < 4; ++n) acc[m][n] = (f32x4){0.f, 0.f, 0.f, 0.f};

  auto stage = [&](int buf, int kt) {
    const int ko = kt * 32;
    gload_lds16(gA0 + ko, &ldsA[buf][ldsOff0]);
    gload_lds16(gA1 + ko, &ldsA[buf][ldsOff1]);
    gload_lds16(gB0 + ko, &ldsB[buf][ldsOff0]);
    gload_lds16(gB1 + ko, &ldsB[buf][ldsOff1]);
  };

  // fragment read offsets (shorts), swizzled: blk' = gp ^ (row&3)
  unsigned aoff[4], boff[4];
#pragma unroll
  for (int m = 0; m < 4; ++m) {
    int row = wr + m * 16 + l15;
    aoff[m] = (unsigned)(row * 32 + ((gp ^ (row & 3)) * 8));
    int col = wc + m * 16 + l15;
    boff[m] = (unsigned)(col * 32 + ((gp ^ (col & 3)) * 8));
  }

  stage(0, 0);
  for (int kt = 0; kt < 32; ++kt) {
    __syncthreads();
    if (kt + 1 < 32) stage((kt + 1) & 1, kt + 1);
    const int cur = kt & 1;
    bf16x8 a[4], b[4];
#pragma unroll
    for (int m = 0; m < 4; ++m) a[m] = *(const bf16x8*)&ldsA[cur][aoff[m]];
#pragma unroll
    for (int n = 0; n < 4; ++n) b[n] = *(const bf16x8*)&ldsB[cur][boff[n]];
#pragma unroll
    for (int m = 0; m < 4; ++m)
#pragma unroll
      for (int n = 0; n < 4; ++n)
        acc[m][n] = __builtin_amdgcn_mfma_f32_16x16x32_bf16(a[m], b[n],
                                                            acc[m][n], 0, 0, 0);
  }

  // epilogue: D layout col=lane&15, row=(lane>>4)*4+reg (m89)
#pragma unroll
  for (int n = 0; n < 4; ++n) {
    const long col = bcol + wc + n * 16 + l15;
    const float bv = bias[col];
#pragma unroll
    for (int m = 0; m < 4; ++m) {
#pragma unroll
      for (int r = 0; r < 4; ++r) {
        const long row = brow + wr + m * 16 + gp * 4 + r;
        const float v = acc[m][n][r] + bv;
        if constexpr (MODE == 0) {
          Cbf[row * KDIM + col] = f2bf(v);
        } else {
          Cf[row * KDIM + col] = v;
          Cf[row * KDIM + col + OUT_HALF] = v;
        }
      }
    }
  }
}

// ---------------------------------------------------------------------------
// Per-token head-axis attention.  One wave per token, 4 waves/block.
// S^T = K.Q^T (swapped) -> softmax over heads via 2 shfl_xor -> P-frag via
// 8 shuffles -> PV (zero-K-padded MFMAs).
// V staged per-wave to XOR-swizzled LDS from 2 vector loads (write uniform
// over all 32 banks; ds_read_u16 gather max 2-way = free per m136); output
// restaged via LDS -> 2 coalesced 16B stores/lane.
// Wave-private LDS: no __syncthreads needed (compiler orders via lgkmcnt).
// ---------------------------------------------------------------------------
__global__ __launch_bounds__(256) void attn_k(
    const unsigned short* __restrict__ qb, const unsigned short* __restrict__ kb,
    const unsigned short* __restrict__ vb, const float* __restrict__ mask,
    unsigned short* __restrict__ attn) {
  __shared__ char vlds[4][2048];
  const int tid = threadIdx.x, lane = tid & 63, w = tid >> 6;
  char* lbuf = vlds[w];
  const long t = (long)blockIdx.x * 4 + w;
  const unsigned short* qr = qb + t * KDIM;
  const unsigned short* kr = kb + t * KDIM;
  const unsigned short* vr = vb + t * KDIM;
  const int l15 = lane & 15, gp = lane >> 4;

  // --- stage V row [16][64] bf16 into wave LDS, XOR-swizzled 16B blocks ---
  {
    const int g = lane >> 2, c = lane & 3;
    uint4 v0 = *(const uint4*)(vr + g * 64 + c * 16);
    uint4 v1 = *(const uint4*)(vr + g * 64 + c * 16 + 8);
    const unsigned s = (unsigned)(((g >> 1) & 7) << 4);
    *(uint4*)(lbuf + (((unsigned)(g * 128 + c * 32)) ^ s)) = v0;
    *(uint4*)(lbuf + (((unsigned)(g * 128 + c * 32 + 16)) ^ s)) = v1;
  }

  // --- QK^T swapped: lane holds S^T[g][h], h=l15, g=gp*4+r ---
  bf16x8 kf0 = *(const bf16x8*)(kr + l15 * 64 + gp * 8);
  bf16x8 kf1 = *(const bf16x8*)(kr + l15 * 64 + 32 + gp * 8);
  bf16x8 qf0 = *(const bf16x8*)(qr + l15 * 64 + gp * 8);
  bf16x8 qf1 = *(const bf16x8*)(qr + l15 * 64 + 32 + gp * 8);
  f32x4 st = {0.f, 0.f, 0.f, 0.f};
  st = __builtin_amdgcn_mfma_f32_16x16x32_bf16(kf0, qf0, st, 0, 0, 0);
  st = __builtin_amdgcn_mfma_f32_16x16x32_bf16(kf1, qf1, st, 0, 0, 0);

  float s[4];
  const float* mrow = mask + t * 256 + l15 * 16 + gp * 4;  // mask[t][h][g]
#pragma unroll
  for (int r = 0; r < 4; ++r) s[r] = st[r] * 0.125f - 1e9f * mrow[r];

  // softmax over g (fixed h=l15): local 4 regs, then lanes ^16, ^32
  float mx = fmaxf(fmaxf(s[0], s[1]), fmaxf(s[2], s[3]));
  mx = fmaxf(mx, __shfl_xor(mx, 16, 64));
  mx = fmaxf(mx, __shfl_xor(mx, 32, 64));
  float p[4], sum = 0.f;
#pragma unroll
  for (int r = 0; r < 4; ++r) { p[r] = __expf(s[r] - mx); sum += p[r]; }
  sum += __shfl_xor(sum, 16, 64);
  sum += __shfl_xor(sum, 32, 64);
  const float inv = 1.0f / sum;
#pragma unroll
  for (int r = 0; r < 4; ++r) p[r] *= inv;

  // --- P A-frag: lane needs P[h=l15][g=gp*8+i]; gp>=2 is zero K-pad ---
  bf16x8 pa;
#pragma unroll
  for (int i = 0; i < 8; ++i) {
    const int g = gp * 8 + i;
    const int src = l15 + 16 * ((g >> 2) & 3);
    const float v = __shfl(p[i & 3], src, 64);
    pa[i] = (gp < 2) ? (short)f2bf(v) : (short)0;
  }

  // --- PV: B-frag gathered from swizzled LDS (address clamped for pad) ---
  float ov[4][4];
#pragma unroll
  for (int nb = 0; nb < 4; ++nb) {
    bf16x8 vf;
#pragma unroll
    for (int i = 0; i < 8; ++i) {
      const int gi = (gp * 8 + i) & 15;
      const unsigned byte =
          ((unsigned)(gi * 128 + (nb * 16 + l15) * 2)) ^
          (unsigned)(((gi >> 1) & 7) << 4);
      const unsigned short val = *(const unsigned short*)(lbuf + byte);
      vf[i] = (gp < 2) ? (short)val : (short)0;
    }
    f32x4 o = {0.f, 0.f, 0.f, 0.f};
    o = __builtin_amdgcn_mfma_f32_16x16x32_bf16(pa, vf, o, 0, 0, 0);
#pragma unroll
    for (int r = 0; r < 4; ++r) ov[nb][r] = o[r];
  }

  // --- restage output [16][64] bf16 via LDS (reuse lbuf), coalesced store ---
#pragma unroll
  for (int nb = 0; nb < 4; ++nb)
#pragma unroll
    for (int r = 0; r < 4; ++r) {
      const int h = gp * 4 + r;
      const unsigned byte =
          ((unsigned)(h * 128 + (nb * 16 + l15) * 2)) ^
          (unsigned)(((h >> 1) & 7) << 4);
      *(unsigned short*)(lbuf + byte) = f2bf(ov[nb][r]);
    }
  {
    const int h = lane >> 2, c = lane & 3;
    const unsigned s2 = (unsigned)(((h >> 1) & 7) << 4);
    uint4 a0 = *(const uint4*)(lbuf + (((unsigned)(h * 128 + c * 32)) ^ s2));
    uint4 a1 = *(const uint4*)(lbuf + (((unsigned)(h * 128 + c * 32 + 16)) ^ s2));
    *(uint4*)(attn + t * KDIM + h * 64 + c * 16) = a0;
    *(uint4*)(attn + t * KDIM + h * 64 + c * 16 + 8) = a1;
  }
}

// ---------------------------------------------------------------------------
extern "C" void kernel_launch(void* const* d_in, const int* in_sizes, int n_in,
                              void* d_out, int out_size, void* d_ws,
                              size_t ws_size, hipStream_t stream) {
  const float* Q  = (const float*)d_in[0];
  const float* K  = (const float*)d_in[1];
  const float* V  = (const float*)d_in[2];
  const float* mask = (const float*)d_in[3];
  const float* Wq = (const float*)d_in[4];
  const float* bq = (const float*)d_in[5];
  const float* Wk = (const float*)d_in[6];
  const float* bk = (const float*)d_in[7];
  const float* Wv = (const float*)d_in[8];
  const float* bv = (const float*)d_in[9];
  const float* Wo = (const float*)d_in[10];
  const float* bo = (const float*)d_in[11];
  float* out = (float*)d_out;

  const size_t EL = (size_t)MTOK * KDIM;
  unsigned short* Qb = (unsigned short*)d_ws;
  unsigned short* Kb = Qb + EL;
  unsigned short* Vb = Kb + EL;
  unsigned short* qb = Vb + EL;
  unsigned short* kb = qb + EL;
  unsigned short* vb = kb + EL;
  unsigned short* Wt = vb + EL;            // 4 x 1M elems
  unsigned short* attnb = Qb;              // Qb dead after proj GEMMs

  const size_t need = (6 * EL + 4ul * 1024 * 1024) * 2;  // 209,715,200 B
  if (ws_size < need) return;

  dim3 b256(256);
  wtrans<<<dim3(256, 4), b256, 0, stream>>>(Wq, Wk, Wv, Wo, Wt);
  castk3<<<dim3(8192, 3), b256, 0, stream>>>(Q, K, V, Qb, Kb, Vb);

  gemm_bt<0, 3072><<<dim3(8, 128, 3), b256, 0, stream>>>(
      Qb, Kb, Vb, Wt, bq, bk, bv, qb, kb, vb, nullptr);

  attn_k<<<4096, b256, 0, stream>>>(qb, kb, vb, mask, attnb);

  gemm_bt<1, 1024><<<dim3(8, 128, 1), b256, 0, stream>>>(
      attnb, attnb, attnb, Wt + 3 * 1048576, bo, bo, bo, nullptr, nullptr,
      nullptr, out);
}